// Round 17
// baseline (152.476 us; speedup 1.0000x reference)
//
#include <hip/hip_runtime.h>
#include <hip/hip_bf16.h>

// LSTM cell fused kernel for MI355X (gfx950).
// B=65536, H=256. Packed GEMM [B,256]x[256,1024] bf16 MFMA + fused gates.
// R17: R16 (verified best 115.6us) + TPB=2 intra-block pipeline.
//      1024 blocks x 512 thr; block = TWO 64-row tiles x one j-half.
//      Stage loads for tile 1 are ISSUED before tile 0's K-loop (64 VGPRs in
//      flight, pinned by a memory-clobber fence so the compiler cannot
//      re-sink them - the R10 failure mode) and written to LDS after.
//      launch_bounds(512,2): 256-reg budget, no spill; 1 block/CU by design.
//      All HBM/L2 traffic identical to R16; only the schedule changes.

typedef __attribute__((ext_vector_type(8))) short short8;   // 8 bf16
typedef __attribute__((ext_vector_type(4))) float f32x4;

static constexpr int Bsz   = 65536;
static constexpr int Hdim  = 256;
static constexpr int TROWS = 64;
static constexpr int NBLK  = (Bsz / (TROWS * 2)) * 2;   // 1024 blocks

// float -> bf16 bits, round-to-nearest-even
__device__ __forceinline__ short f2bf(float f) {
    unsigned u = __float_as_uint(f);
    return (short)((u + 0x7FFFu + ((u >> 16) & 1u)) >> 16);
}
__device__ __forceinline__ float fast_rcp(float x) {
    float r;
    asm("v_rcp_f32 %0, %1" : "=v"(r) : "v"(x));
    return r;
}
__device__ __forceinline__ float sigm(float x) {
    return fast_rcp(1.0f + __expf(-x));
}
__device__ __forceinline__ float tanh_fast(float x) {
    return 2.0f * fast_rcp(1.0f + __expf(-2.0f * x)) - 1.0f;
}

// ---------------------------------------------------------------------------
// Pack Wf,Wc,Wi,Wo ([256,256] fp32) into bf16 B-fragment-major layout for
// mfma_f32_16x16x32_bf16 (verified R2..R16):
//   flat o = (((g*8 + ks)*16 + jf)*64 + lane)*8 + e
//   k = ks*32 + (lane>>4)*8 + e ;  j = jf*16 + (lane&15) ;  B[k][j] = W_g[j][k]
// ---------------------------------------------------------------------------
__global__ void __launch_bounds__(256)
prep_w_kernel(const float* __restrict__ Wf, const float* __restrict__ Wc,
              const float* __restrict__ Wi, const float* __restrict__ Wo,
              short* __restrict__ Bp)
{
    int o    = blockIdx.x * 256 + threadIdx.x;   // 0 .. 262143
    int e    = o & 7;
    int lane = (o >> 3) & 63;
    int jf   = (o >> 9) & 15;
    int ks   = (o >> 13) & 7;
    int g    = (o >> 16) & 3;
    int k = ks * 32 + (lane >> 4) * 8 + e;
    int j = jf * 16 + (lane & 15);
    const float* W = (g == 0) ? Wf : (g == 1) ? Wc : (g == 2) ? Wi : Wo;
    Bp[o] = f2bf(W[j * 256 + k]);
}

// ---------------------------------------------------------------------------
// Main. 1024 blocks x 512 threads (8 waves). Block = 128 rows (2 tiles of 64)
// x 128 gate-cols (one j-half) x 4 gates. Wave w owns j in [jh*128+w*16,+16)
// for all rows -> acc[4][4] = 64 VGPRs per tile (reused across tiles).
// bid = 16a + 8h + b: rowpair = 8a + b, jh = h -> the 2 j-siblings of a
// row-pair share an XCD (combine L2 reuse + store-line merging in L2).
// Pipeline: issue(0) | write(0) | bar | issue(1) | K(0) | write(1) | bar |
//           epi(0) | K(1) | epi(1)
// ---------------------------------------------------------------------------
__global__ void __launch_bounds__(512, 2)
lstm_main(const float* __restrict__ inp, const float* __restrict__ hid,
          const float* __restrict__ cell, const short* __restrict__ Bp,
          const float* __restrict__ bfv, const float* __restrict__ bcv,
          const float* __restrict__ biv, const float* __restrict__ bov,
          float* __restrict__ out)
{
    __shared__ short As[2][TROWS * Hdim];   // 2 x 32 KB swizzled combine tiles

    const int tid  = threadIdx.x;
    const int lane = tid & 63;
    const int wave = tid >> 6;           // 0..7
    const int lm   = lane & 15;
    const int lk   = lane >> 4;

    const int bid     = blockIdx.x;
    const int rowpair = (bid >> 4) * 8 + (bid & 7);   // 0..511
    const int jh      = (bid >> 3) & 1;
    const int rowblk  = rowpair * (TROWS * 2);

    const int j         = jh * 128 + wave * 16 + lm;  // this lane's gate-col
    const int jf_global = jh * 8 + wave;              // j / 16

    // staging coords: 2048 16B-chunks per tile, 512 threads x 4 chunks
    const int s_row = tid >> 5;          // 0..15 (+16*c per chunk)
    // NOTE: chunk c covers rows [c*16, c*16+16) via row = (tid + c*512) >> 5
    const int s_k0  = (tid & 31) * 8;    // 0..248

    float4 Li[4][2], Lh[4][2];           // 64 VGPRs in flight while pipelined

    auto issue = [&](int t) {
#pragma unroll
        for (int c = 0; c < 4; ++c) {
            int row = s_row + c * 16;    // (tid + c*512)>>5 == s_row + c*16
            const float4* ip = reinterpret_cast<const float4*>(
                inp + (size_t)(rowblk + t * TROWS + row) * Hdim + s_k0);
            const float4* hp = reinterpret_cast<const float4*>(
                hid + (size_t)(rowblk + t * TROWS + row) * Hdim + s_k0);
            Li[c][0] = ip[0]; Li[c][1] = ip[1];
            Lh[c][0] = hp[0]; Lh[c][1] = hp[1];
        }
    };
    auto writeb = [&](int buf) {
#pragma unroll
        for (int c = 0; c < 4; ++c) {
            int row = s_row + c * 16;
            short8 v;
            v[0] = f2bf(Li[c][0].x + Lh[c][0].x);
            v[1] = f2bf(Li[c][0].y + Lh[c][0].y);
            v[2] = f2bf(Li[c][0].z + Lh[c][0].z);
            v[3] = f2bf(Li[c][0].w + Lh[c][0].w);
            v[4] = f2bf(Li[c][1].x + Lh[c][1].x);
            v[5] = f2bf(Li[c][1].y + Lh[c][1].y);
            v[6] = f2bf(Li[c][1].z + Lh[c][1].z);
            v[7] = f2bf(Li[c][1].w + Lh[c][1].w);
            int byte = (row * 512 + s_k0 * 2) ^ ((row & 7) << 4);
            *reinterpret_cast<short8*>(
                reinterpret_cast<char*>(As[buf]) + byte) = v;
        }
    };

    // bias per lane (j fixed) — only 4 regs live throughout
    const float bF = bfv[j], bC = bcv[j], bI = biv[j], bO = bov[j];

    auto kloop = [&](const short* Abuf, f32x4 (&acc)[4][4]) {
        acc[0][0] = (f32x4){bF, bF, bF, bF};
        acc[1][0] = (f32x4){bC, bC, bC, bC};
        acc[2][0] = (f32x4){bI, bI, bI, bI};
        acc[3][0] = (f32x4){bO, bO, bO, bO};
#pragma unroll
        for (int g = 0; g < 4; ++g)
#pragma unroll
            for (int mf = 1; mf < 4; ++mf)
                acc[g][mf] = acc[g][0];
        const char* A = reinterpret_cast<const char*>(Abuf);
#pragma unroll
        for (int ks = 0; ks < 8; ++ks) {
            short8 cf[4];
#pragma unroll
            for (int mf = 0; mf < 4; ++mf) {
                int row  = mf * 16 + lm;
                int byte = (row * 512 + (ks * 32 + lk * 8) * 2) ^ ((row & 7) << 4);
                cf[mf] = *reinterpret_cast<const short8*>(A + byte);
            }
#pragma unroll
            for (int g = 0; g < 4; ++g) {
                int chunk = (g * 8 + ks) * 16 + jf_global;
                short8 b = *reinterpret_cast<const short8*>(
                               Bp + ((size_t)chunk * 64 + lane) * 8);
                acc[g][0] = __builtin_amdgcn_mfma_f32_16x16x32_bf16(cf[0], b, acc[g][0], 0, 0, 0);
                acc[g][1] = __builtin_amdgcn_mfma_f32_16x16x32_bf16(cf[1], b, acc[g][1], 0, 0, 0);
                acc[g][2] = __builtin_amdgcn_mfma_f32_16x16x32_bf16(cf[2], b, acc[g][2], 0, 0, 0);
                acc[g][3] = __builtin_amdgcn_mfma_f32_16x16x32_bf16(cf[3], b, acc[g][3], 0, 0, 0);
            }
        }
    };

    float* out0 = out;                               // out gate
    float* out1 = out + (size_t)Bsz * Hdim;          // hidden_state
    float* out2 = out + (size_t)2 * Bsz * Hdim;      // cell_state

    auto epilogue = [&](int t, f32x4 (&acc)[4][4]) {
        const int r0 = rowblk + t * TROWS;
#pragma unroll
        for (int mf = 0; mf < 4; ++mf) {
            float cv[4];
#pragma unroll
            for (int r = 0; r < 4; ++r)
                cv[r] = cell[(size_t)(r0 + mf * 16 + lk * 4 + r) * Hdim + j];
#pragma unroll
            for (int r = 0; r < 4; ++r) {
                int row = r0 + mf * 16 + lk * 4 + r;   // C/D: row=(lane>>4)*4+reg
                size_t off = (size_t)row * Hdim + j;
                float F = sigm(acc[0][mf][r]);
                float C = tanh_fast(acc[1][mf][r]);
                float I = sigm(sigm(acc[2][mf][r]));   // double sigmoid, per ref
                float O = sigm(acc[3][mf][r]);
                float cs = cv[r] * F + C * I;
                float hs = O * tanh_fast(cs);
                out0[off] = O;
                out1[off] = hs;
                out2[off] = cs;
            }
        }
    };

    // ---- pipeline ---------------------------------------------------------
    issue(0);
    asm volatile("" ::: "memory");       // pin issue point
    writeb(0);                           // compiler inserts vmcnt wait
    __syncthreads();                     // As[0] ready

    issue(1);                            // tile-1 loads in flight during K(0)
    asm volatile("" ::: "memory");       // forbid re-sinking past this point

    f32x4 acc[4][4];                     // 64 VGPRs, reused across tiles
    kloop(As[0], acc);

    writeb(1);                           // vmcnt drain + LDS write
    __syncthreads();                     // As[1] ready

    epilogue(0, acc);                    // stores overlap next K-loop's L2 reads
    kloop(As[1], acc);
    epilogue(1, acc);
}

extern "C" void kernel_launch(void* const* d_in, const int* in_sizes, int n_in,
                              void* d_out, int out_size, void* d_ws, size_t ws_size,
                              hipStream_t stream)
{
    const float* inp  = (const float*)d_in[0];
    const float* hid  = (const float*)d_in[1];
    const float* cell = (const float*)d_in[2];
    const float* Wf   = (const float*)d_in[3];
    const float* bf_  = (const float*)d_in[4];
    const float* Wc   = (const float*)d_in[5];
    const float* bc_  = (const float*)d_in[6];
    const float* Wi   = (const float*)d_in[7];
    const float* bi_  = (const float*)d_in[8];
    const float* Wo   = (const float*)d_in[9];
    const float* bo_  = (const float*)d_in[10];

    short* Bp = (short*)d_ws;    // 512 KB packed bf16 weights

    prep_w_kernel<<<1024, 256, 0, stream>>>(Wf, Wc, Wi, Wo, Bp);
    lstm_main<<<NBLK, 512, 0, stream>>>(inp, hid, cell, Bp,
                                        bf_, bc_, bi_, bo_, (float*)d_out);
}

// Round 18
// 114.762 us; speedup vs baseline: 1.3286x; 1.3286x over previous
//
#include <hip/hip_runtime.h>
#include <hip/hip_bf16.h>

// LSTM cell fused kernel for MI355X (gfx950).
// B=65536, H=256. Packed GEMM [B,256]x[256,1024] bf16 MFMA + fused gates.
// FINAL = R12/R16 (verified best: 115.6us, clean counters, reproduced twice).
//      TROWS=64 weight amortization: 2048 blocks x 512 thr (8 waves); block =
//      64 rows x 128 j-half; wave = 64r x 16j x 4 gates (acc[4][4]=64).
//      Every weight fragment loaded once per block. Staging in 2 rounds of 2
//      chunks, cell loaded AFTER GEMM, bias pre-barrier, scalar stores.
//
// Session notes (15 structural variants benched):
//  - Confirmed lever: weight-re-read mass (1 GB -> 512 MB was -20us, R12).
//  - Refuted levers: occupancy>4w/SIMD (R6: +issue work, -perf), 4 blocks/CU
//    with x4 restaging (R14), TA-lean transposed epilogue (R15: 64B half-line
//    RMW amplification), weights-in-VGPR (R13: spill), barrier-free (R7),
//    split-prep (R9: serial prep cost), intra-block pipeline (R17: loses
//    inter-block TLP at 1 block/CU).
//  - Plateau: stage->barrier->K-loop phase serialization; ~2.3x the 50us
//    traffic floor; all pipes <42% busy.

typedef __attribute__((ext_vector_type(8))) short short8;   // 8 bf16
typedef __attribute__((ext_vector_type(4))) float f32x4;

static constexpr int Bsz   = 65536;
static constexpr int Hdim  = 256;
static constexpr int TROWS = 64;
static constexpr int NBLK  = (Bsz / TROWS) * 2;   // 2048 blocks (2 j-halves)

// float -> bf16 bits, round-to-nearest-even
__device__ __forceinline__ short f2bf(float f) {
    unsigned u = __float_as_uint(f);
    return (short)((u + 0x7FFFu + ((u >> 16) & 1u)) >> 16);
}
__device__ __forceinline__ float fast_rcp(float x) {
    float r;
    asm("v_rcp_f32 %0, %1" : "=v"(r) : "v"(x));
    return r;
}
__device__ __forceinline__ float sigm(float x) {
    return fast_rcp(1.0f + __expf(-x));
}
__device__ __forceinline__ float tanh_fast(float x) {
    return 2.0f * fast_rcp(1.0f + __expf(-2.0f * x)) - 1.0f;
}

// ---------------------------------------------------------------------------
// Pack Wf,Wc,Wi,Wo ([256,256] fp32) into bf16 B-fragment-major layout for
// mfma_f32_16x16x32_bf16 (verified R2..R17):
//   flat o = (((g*8 + ks)*16 + jf)*64 + lane)*8 + e
//   k = ks*32 + (lane>>4)*8 + e ;  j = jf*16 + (lane&15) ;  B[k][j] = W_g[j][k]
// ---------------------------------------------------------------------------
__global__ void __launch_bounds__(256)
prep_w_kernel(const float* __restrict__ Wf, const float* __restrict__ Wc,
              const float* __restrict__ Wi, const float* __restrict__ Wo,
              short* __restrict__ Bp)
{
    int o    = blockIdx.x * 256 + threadIdx.x;   // 0 .. 262143
    int e    = o & 7;
    int lane = (o >> 3) & 63;
    int jf   = (o >> 9) & 15;
    int ks   = (o >> 13) & 7;
    int g    = (o >> 16) & 3;
    int k = ks * 32 + (lane >> 4) * 8 + e;
    int j = jf * 16 + (lane & 15);
    const float* W = (g == 0) ? Wf : (g == 1) ? Wc : (g == 2) ? Wi : Wo;
    Bp[o] = f2bf(W[j * 256 + k]);
}

// ---------------------------------------------------------------------------
// Main. 2048 blocks x 512 threads (8 waves). Block = 64 rows x 128 gate-cols
// (one j-half) x 4 gates. Wave w owns j in [jh*128 + w*16, +16) for ALL
// 64 rows -> acc[4][4] = 64 VGPRs; weight fragments unique per wave & block.
// bid = 16a + 8h + b: rowtile = 8a + b, jh = h -> the 2 j-siblings of a
// rowtile share an XCD (combine L2 reuse + store-line merging in L2).
// ---------------------------------------------------------------------------
__global__ void __launch_bounds__(512, 4)
lstm_main(const float* __restrict__ inp, const float* __restrict__ hid,
          const float* __restrict__ cell, const short* __restrict__ Bp,
          const float* __restrict__ bfv, const float* __restrict__ bcv,
          const float* __restrict__ biv, const float* __restrict__ bov,
          float* __restrict__ out)
{
    __shared__ short As[TROWS * Hdim];   // 32 KB swizzled combine tile

    const int tid  = threadIdx.x;
    const int lane = tid & 63;
    const int wave = tid >> 6;           // 0..7
    const int lm   = lane & 15;
    const int lk   = lane >> 4;

    const int bid     = blockIdx.x;
    const int rowtile = (bid >> 4) * 8 + (bid & 7);   // 0..1023
    const int jh      = (bid >> 3) & 1;
    const int rowblk  = rowtile * TROWS;

    const int j         = jh * 128 + wave * 16 + lm;  // this lane's gate-col
    const int jf_global = jh * 8 + wave;              // j / 16

    // ---- stage combine = input + hidden (bf16) into LDS, XOR-swizzled -----
    // 2048 16B-chunks; 512 threads x 4 chunks, in 2 rounds of 2 (reg cap).
#pragma unroll
    for (int round = 0; round < 2; ++round) {
        float4 Li[2][2], Lh[2][2];
#pragma unroll
        for (int c = 0; c < 2; ++c) {
            int cc  = tid + (round * 2 + c) * 512;    // chunk 0..2047
            int row = cc >> 5;                        // 0..63
            int k0  = (cc & 31) * 8;                  // 0..248
            const float4* ip = reinterpret_cast<const float4*>(inp + (size_t)(rowblk + row) * Hdim + k0);
            const float4* hp = reinterpret_cast<const float4*>(hid + (size_t)(rowblk + row) * Hdim + k0);
            Li[c][0] = ip[0]; Li[c][1] = ip[1];
            Lh[c][0] = hp[0]; Lh[c][1] = hp[1];
        }
#pragma unroll
        for (int c = 0; c < 2; ++c) {
            int cc  = tid + (round * 2 + c) * 512;
            int row = cc >> 5;
            int k0  = (cc & 31) * 8;
            short8 v;
            v[0] = f2bf(Li[c][0].x + Lh[c][0].x);
            v[1] = f2bf(Li[c][0].y + Lh[c][0].y);
            v[2] = f2bf(Li[c][0].z + Lh[c][0].z);
            v[3] = f2bf(Li[c][0].w + Lh[c][0].w);
            v[4] = f2bf(Li[c][1].x + Lh[c][1].x);
            v[5] = f2bf(Li[c][1].y + Lh[c][1].y);
            v[6] = f2bf(Li[c][1].z + Lh[c][1].z);
            v[7] = f2bf(Li[c][1].w + Lh[c][1].w);
            int byte = (row * 512 + k0 * 2) ^ ((row & 7) << 4);
            *reinterpret_cast<short8*>(reinterpret_cast<char*>(As) + byte) = v;
        }
    }

    // bias per lane (j fixed) — only 4 regs live through the GEMM
    const float bF = bfv[j], bC = bcv[j], bI = biv[j], bO = bov[j];

    __syncthreads();                     // As visible

    // ---- acc init = bias --------------------------------------------------
    f32x4 acc[4][4];                     // [gate][mf] = 64 VGPRs
    acc[0][0] = (f32x4){bF, bF, bF, bF};
    acc[1][0] = (f32x4){bC, bC, bC, bC};
    acc[2][0] = (f32x4){bI, bI, bI, bI};
    acc[3][0] = (f32x4){bO, bO, bO, bO};
#pragma unroll
    for (int g = 0; g < 4; ++g)
#pragma unroll
        for (int mf = 1; mf < 4; ++mf)
            acc[g][mf] = acc[g][0];

    // ---- GEMM: K=256 in 8 steps; 4 ds_read + 4 weight loads + 16 MFMA -----
    const char* A = reinterpret_cast<const char*>(As);
#pragma unroll
    for (int ks = 0; ks < 8; ++ks) {
        short8 cf[4];
#pragma unroll
        for (int mf = 0; mf < 4; ++mf) {
            int row  = mf * 16 + lm;
            int byte = (row * 512 + (ks * 32 + lk * 8) * 2) ^ ((row & 7) << 4);
            cf[mf] = *reinterpret_cast<const short8*>(A + byte);
        }
#pragma unroll
        for (int g = 0; g < 4; ++g) {
            int chunk = (g * 8 + ks) * 16 + jf_global;
            short8 b = *reinterpret_cast<const short8*>(
                           Bp + ((size_t)chunk * 64 + lane) * 8);   // 1KB, contig
            acc[g][0] = __builtin_amdgcn_mfma_f32_16x16x32_bf16(cf[0], b, acc[g][0], 0, 0, 0);
            acc[g][1] = __builtin_amdgcn_mfma_f32_16x16x32_bf16(cf[1], b, acc[g][1], 0, 0, 0);
            acc[g][2] = __builtin_amdgcn_mfma_f32_16x16x32_bf16(cf[2], b, acc[g][2], 0, 0, 0);
            acc[g][3] = __builtin_amdgcn_mfma_f32_16x16x32_bf16(cf[3], b, acc[g][3], 0, 0, 0);
        }
    }

    // ---- cell loads AFTER GEMM (not live through K-loop) ------------------
    float* out0 = out;                               // out gate
    float* out1 = out + (size_t)Bsz * Hdim;          // hidden_state
    float* out2 = out + (size_t)2 * Bsz * Hdim;      // cell_state

#pragma unroll
    for (int mf = 0; mf < 4; ++mf) {
        float cv[4];
#pragma unroll
        for (int r = 0; r < 4; ++r)
            cv[r] = cell[(size_t)(rowblk + mf * 16 + lk * 4 + r) * Hdim + j];
#pragma unroll
        for (int r = 0; r < 4; ++r) {
            int row = rowblk + mf * 16 + lk * 4 + r;   // C/D: row=(lane>>4)*4+reg
            size_t off = (size_t)row * Hdim + j;
            float F = sigm(acc[0][mf][r]);
            float C = tanh_fast(acc[1][mf][r]);
            float I = sigm(sigm(acc[2][mf][r]));       // double sigmoid, per ref
            float O = sigm(acc[3][mf][r]);
            float cs = cv[r] * F + C * I;
            float hs = O * tanh_fast(cs);
            out0[off] = O;
            out1[off] = hs;
            out2[off] = cs;
        }
    }
}

extern "C" void kernel_launch(void* const* d_in, const int* in_sizes, int n_in,
                              void* d_out, int out_size, void* d_ws, size_t ws_size,
                              hipStream_t stream)
{
    const float* inp  = (const float*)d_in[0];
    const float* hid  = (const float*)d_in[1];
    const float* cell = (const float*)d_in[2];
    const float* Wf   = (const float*)d_in[3];
    const float* bf_  = (const float*)d_in[4];
    const float* Wc   = (const float*)d_in[5];
    const float* bc_  = (const float*)d_in[6];
    const float* Wi   = (const float*)d_in[7];
    const float* bi_  = (const float*)d_in[8];
    const float* Wo   = (const float*)d_in[9];
    const float* bo_  = (const float*)d_in[10];

    short* Bp = (short*)d_ws;    // 512 KB packed bf16 weights

    prep_w_kernel<<<1024, 256, 0, stream>>>(Wf, Wc, Wi, Wo, Bp);
    lstm_main<<<NBLK, 512, 0, stream>>>(inp, hid, cell, Bp,
                                        bf_, bc_, bi_, bo_, (float*)d_out);
}